// Round 1
// baseline (149.063 us; speedup 1.0000x reference)
//
#include <hip/hip_runtime.h>

#define NB 4096
#define NM 64
#define ND 64
#define NK 256
#define BROWS 64
#define NTHREADS 512

#define IDX_BASE 16777216UL   // 4096*64*64
#define LOSS_IDX 17039360UL   // IDX_BASE + 4096*64

// Block = one codebook m  x  64 z-rows. LDS: swizzled codebook (64KB) + z tile (16KB) = 80KB -> 2 blocks/CU.
__global__ __launch_bounds__(NTHREADS, 4) void pq_main(
    const float* __restrict__ z, const float* __restrict__ cb,
    float* __restrict__ out, float* __restrict__ partial)
{
    __shared__ float sC[NK * ND];      // swizzled: (k, j=jg*4+e) -> sC[k*64 + ((jg ^ ((k>>3)&7))<<2) + e]
    __shared__ float sZ[BROWS * ND];   // linear
    int*   sBest = (int*)sC;           // aliases sC after main loop (guarded by barriers)
    float* sWred = sC + 64;

    const int tid   = threadIdx.x;
    const int bx    = blockIdx.x;
    const int m     = bx >> 6;         // 64 chunks per m, consecutive -> codebook L2 locality
    const int chunk = bx & 63;
    const int b0    = chunk * BROWS;

    const float* cbm = cb + (size_t)m * (NK * ND);

    // ---- stage codebook (swizzled), 4096 float4 ----
    #pragma unroll
    for (int it = 0; it < 8; ++it) {
        int i4 = tid + it * NTHREADS;
        int k  = i4 >> 4;
        int jg = i4 & 15;
        float4 v = reinterpret_cast<const float4*>(cbm)[i4];
        int sw = (k >> 3) & 7;
        *reinterpret_cast<float4*>(&sC[k * 64 + ((jg ^ sw) << 2)]) = v;
    }
    // ---- stage z tile (linear), 1024 float4 ----
    #pragma unroll
    for (int it = 0; it < 2; ++it) {
        int i4 = tid + it * NTHREADS;
        int r  = i4 >> 4;
        int jg = i4 & 15;
        float4 v = reinterpret_cast<const float4*>(z + (size_t)(b0 + r) * (NM * ND) + m * ND)[jg];
        *reinterpret_cast<float4*>(&sZ[r * 64 + (jg << 2)]) = v;
    }
    __syncthreads();

    const int cg  = tid & 63;          // code group: codes 4cg..4cg+3
    const int rg  = tid >> 6;          // row group:  rows 8rg..8rg+7 (wave-uniform!)
    const int k0  = cg << 2;
    const int r0  = rg << 3;
    const int sf4 = ((cg >> 1) & 7) << 2;   // shared swizzle for all 4 codes of this thread (floats)

    const float* cbase = &sC[k0 * 64];
    const float* zbase = &sZ[r0 * 64];

    // ---- per-thread c2 for its 4 codes ----
    float c2r[4] = {0.f, 0.f, 0.f, 0.f};
    #pragma unroll
    for (int jg = 0; jg < 16; ++jg) {
        const float* cp = cbase + (((jg << 2) ^ sf4));
        #pragma unroll
        for (int q = 0; q < 4; ++q) {
            float4 v = *reinterpret_cast<const float4*>(cp + q * 64);
            c2r[q] = fmaf(v.x, v.x, c2r[q]);
            c2r[q] = fmaf(v.y, v.y, c2r[q]);
            c2r[q] = fmaf(v.z, v.z, c2r[q]);
            c2r[q] = fmaf(v.w, v.w, c2r[q]);
        }
    }

    // ---- main loop: acc[p][q] = dot(z_row(r0+p), code(k0+q)) ----
    float acc[8][4];
    #pragma unroll
    for (int p = 0; p < 8; ++p)
        #pragma unroll
        for (int q = 0; q < 4; ++q) acc[p][q] = 0.f;

    #pragma unroll
    for (int jg = 0; jg < 16; ++jg) {
        float4 cv[4], zv[8];
        const float* cp = cbase + (((jg << 2) ^ sf4));   // swizzled c: banks spread by per-lane sf4
        #pragma unroll
        for (int q = 0; q < 4; ++q) cv[q] = *reinterpret_cast<const float4*>(cp + q * 64);
        #pragma unroll
        for (int p = 0; p < 8; ++p)                      // wave-uniform addr -> LDS broadcast
            zv[p] = *reinterpret_cast<const float4*>(zbase + p * 64 + (jg << 2));
        #pragma unroll
        for (int p = 0; p < 8; ++p) {
            #pragma unroll
            for (int q = 0; q < 4; ++q) {
                acc[p][q] = fmaf(zv[p].x, cv[q].x, acc[p][q]);
                acc[p][q] = fmaf(zv[p].y, cv[q].y, acc[p][q]);
                acc[p][q] = fmaf(zv[p].z, cv[q].z, acc[p][q]);
                acc[p][q] = fmaf(zv[p].w, cv[q].w, acc[p][q]);
            }
        }
    }

    // ---- per-thread argmin (k ascending, strict < => first-min tiebreak) ----
    float bd[8]; int bk[8];
    #pragma unroll
    for (int p = 0; p < 8; ++p) { bd[p] = 3.4e38f; bk[p] = 0; }
    #pragma unroll
    for (int q = 0; q < 4; ++q) {
        #pragma unroll
        for (int p = 0; p < 8; ++p) {
            float d = fmaf(-2.f, acc[p][q], c2r[q]);   // z2 omitted: constant per row
            if (d < bd[p]) { bd[p] = d; bk[p] = k0 + q; }
        }
    }
    // ---- cross-lane reduce over 64 code-groups, smaller-k wins ties ----
    #pragma unroll
    for (int off = 1; off < 64; off <<= 1) {
        #pragma unroll
        for (int p = 0; p < 8; ++p) {
            float od = __shfl_xor(bd[p], off, 64);
            int   ok = __shfl_xor(bk[p], off, 64);
            if (od < bd[p] || (od == bd[p] && ok < bk[p])) { bd[p] = od; bk[p] = ok; }
        }
    }

    __syncthreads();                    // everyone done reading sC
    if (cg == 0) {
        #pragma unroll
        for (int p = 0; p < 8; ++p) sBest[r0 + p] = bk[p];
    }
    __syncthreads();

    // ---- outputs: quantized rows (exact codebook copy), indices, loss partial ----
    float lsum = 0.f;
    {
        int r  = tid >> 3;
        int c0 = (tid & 7) << 3;
        int ks = sBest[r];
        const float* qrow = cbm + ks * 64;
        float4 q0 = *reinterpret_cast<const float4*>(qrow + c0);
        float4 q1 = *reinterpret_cast<const float4*>(qrow + c0 + 4);
        float4 z0 = *reinterpret_cast<const float4*>(&sZ[r * 64 + c0]);
        float4 z1 = *reinterpret_cast<const float4*>(&sZ[r * 64 + c0 + 4]);
        size_t ob = (size_t)(b0 + r) * (NM * ND) + m * ND + c0;
        *reinterpret_cast<float4*>(out + ob)     = q0;
        *reinterpret_cast<float4*>(out + ob + 4) = q1;
        float d;
        d = q0.x - z0.x; lsum = fmaf(d, d, lsum);
        d = q0.y - z0.y; lsum = fmaf(d, d, lsum);
        d = q0.z - z0.z; lsum = fmaf(d, d, lsum);
        d = q0.w - z0.w; lsum = fmaf(d, d, lsum);
        d = q1.x - z1.x; lsum = fmaf(d, d, lsum);
        d = q1.y - z1.y; lsum = fmaf(d, d, lsum);
        d = q1.z - z1.z; lsum = fmaf(d, d, lsum);
        d = q1.w - z1.w; lsum = fmaf(d, d, lsum);
    }
    if (tid < BROWS) {
        out[IDX_BASE + (size_t)(b0 + tid) * NM + m] = (float)sBest[tid];
    }
    #pragma unroll
    for (int off = 1; off < 64; off <<= 1) lsum += __shfl_xor(lsum, off, 64);
    if ((tid & 63) == 0) sWred[tid >> 6] = lsum;
    __syncthreads();
    if (tid == 0) {
        float t = 0.f;
        #pragma unroll
        for (int w = 0; w < 8; ++w) t += sWred[w];
        partial[bx] = t;
    }
}

// Deterministic final reduction of 4096 block partials -> q_loss
__global__ __launch_bounds__(256) void pq_loss(const float* __restrict__ partial,
                                               float* __restrict__ out)
{
    __shared__ float sW[4];
    float s = 0.f;
    #pragma unroll
    for (int i = 0; i < 16; ++i) s += partial[threadIdx.x + i * 256];
    #pragma unroll
    for (int off = 1; off < 64; off <<= 1) s += __shfl_xor(s, off, 64);
    if ((threadIdx.x & 63) == 0) sW[threadIdx.x >> 6] = s;
    __syncthreads();
    if (threadIdx.x == 0)
        out[LOSS_IDX] = (sW[0] + sW[1] + sW[2] + sW[3]) * (1.25f / 16777216.0f);
}

extern "C" void kernel_launch(void* const* d_in, const int* in_sizes, int n_in,
                              void* d_out, int out_size, void* d_ws, size_t ws_size,
                              hipStream_t stream) {
    const float* zp  = (const float*)d_in[0];
    const float* cbp = (const float*)d_in[1];
    float* outp = (float*)d_out;
    float* part = (float*)d_ws;   // 4096 floats

    pq_main<<<dim3(4096), dim3(NTHREADS), 0, stream>>>(zp, cbp, outp, part);
    pq_loss<<<dim3(1), dim3(256), 0, stream>>>(part, outp);
}